// Round 9
// baseline (1087.842 us; speedup 1.0000x reference)
//
#include <hip/hip_runtime.h>
#include <stdint.h>

#define B_ 8
#define L_ 2500
#define D_ 512
#define Y_ 8921
#define LP 2560   // padded L = 20*128
#define YP 8960   // padded Y = 70*128
#define BLK 128   // y-tile and l-tile
#define BK 32
#define NKT 16    // 512/32
#define NS 4      // l-splits
#define LTS 5     // l-tiles of 128 per split (20/NS)
#define NBLK (70 * B_ * NS)   // 2240 blocks
#define PERX (NBLK / 8)       // 280 work items per XCD

typedef float f32x4 __attribute__((ext_vector_type(4)));
typedef __bf16 bf16x8 __attribute__((ext_vector_type(8)));
typedef unsigned short u16;
typedef unsigned int u32;

// ---- f32 -> bf16 (RTNE) pack helpers ----
__device__ __forceinline__ u32 pack2(float a, float b) {
  u32 ua = __float_as_uint(a); ua = (ua + 0x7FFFu + ((ua >> 16) & 1u)) >> 16;
  u32 ub = __float_as_uint(b); ub = (ub + 0x7FFFu + ((ub >> 16) & 1u)) >> 16;
  return ua | (ub << 16);
}

// x [B,L,D] f32 -> [B,LP,D] bf16 (pad rows zero)
__global__ void cvt_x_kernel(const float* __restrict__ x, u16* __restrict__ xb) {
  int idx = blockIdx.x * 256 + threadIdx.x;   // one 8-elem chunk
  int row = idx >> 6;                         // b*LP + l
  int c8  = (idx & 63) << 3;
  int b = row / LP;
  int l = row - b * LP;
  uint4 o;
  if (l < L_) {
    const float* s = x + (size_t)(b * L_ + l) * D_ + c8;
    float4 f0 = *(const float4*)s;
    float4 f1 = *(const float4*)(s + 4);
    o.x = pack2(f0.x, f0.y); o.y = pack2(f0.z, f0.w);
    o.z = pack2(f1.x, f1.y); o.w = pack2(f1.z, f1.w);
  } else {
    o = make_uint4(0u, 0u, 0u, 0u);
  }
  *(uint4*)(xb + (size_t)row * D_ + c8) = o;
}

// U,Wf [Y,D] f32 -> [YP,D] bf16 each (pad rows zero)
__global__ void cvt_w_kernel(const float* __restrict__ U, const float* __restrict__ Wf,
                             u16* __restrict__ Ub, u16* __restrict__ Wb) {
  int idx = blockIdx.x * 256 + threadIdx.x;
  const int half = YP * 64;
  const float* src = U; u16* dst = Ub;
  int i = idx;
  if (idx >= half) { i -= half; src = Wf; dst = Wb; }
  int row = i >> 6;
  int c8  = (i & 63) << 3;
  uint4 o;
  if (row < Y_) {
    const float* s = src + (size_t)row * D_ + c8;
    float4 f0 = *(const float4*)s;
    float4 f1 = *(const float4*)(s + 4);
    o.x = pack2(f0.x, f0.y); o.y = pack2(f0.z, f0.w);
    o.z = pack2(f1.x, f1.y); o.w = pack2(f1.z, f1.w);
  } else {
    o = make_uint4(0u, 0u, 0u, 0u);
  }
  *(uint4*)(dst + (size_t)row * D_ + c8) = o;
}

// Fused per (y-tile 128, b, l-split): stream LTS l-tiles of 128, MFMA att & s,
// per-lane online softmax (cross-lane merge once at kernel end).
//
// R0-R8 established: the 4-wave LOCKSTEP block structure itself is the ~503us
// ceiling (MfmaUtil pinned ~32% across all staging/occupancy/barrier variants
// -- the m97-structure ceiling). THIS round removes the lockstep: NO LDS, NO
// barriers in the main loop. Each wave free-runs {12 global loads -> 32 MFMA}
// per kt; the 8 waves/CU decorrelate and feed the MFMA pipe statistically.
// X-fragment reads are per-wave from global (16 coalesced lines per wave-op),
// made affordable by flipping the XCD swizzle to (b,s)-slow / yt-fast: the
// ~32 concurrent blocks on an XCD share ONE 655 KB X slice (L2-resident);
// U/W is the streamed operand (2.8 GB aggregate, L2/L3).
//
// Partial layout: part[((b*70 + yt)*NS + s)*384 + {0,128,256} + ylocal]
__global__ __launch_bounds__(256, 2) void fused_kernel(
    const u16* __restrict__ xb,   // [B][LP][D] bf16
    const u16* __restrict__ Ub,   // [YP][D]
    const u16* __restrict__ Wb,   // [YP][D]
    float* __restrict__ part)
{
  const int t    = threadIdx.x;
  const int lane = t & 63;
  const int wv   = t >> 6;          // wave 0..3, owns y rows [wv*32, wv*32+32)
  const int l16  = lane & 15;
  const int q    = lane >> 4;       // quad 0..3

  // Swizzle: bid%8 = XCD (round-robin dispatch). Within an XCD: (b,s) slow,
  // yt FAST -> concurrent blocks share the same X slice (L2-resident).
  const int bid = blockIdx.x;
  const int i   = bid >> 3;         // 0..279
  const int c4  = i / 70;           // 0..3  (local combo)
  const int yt  = i - c4 * 70;      // 0..69 (fast)
  const int combo = (bid & 7) * 4 + c4;   // 0..31
  const int b   = combo >> 2;       // 0..7
  const int s   = combo & 3;        // l-split 0..3
  const int y0  = yt * BLK;

  // A-fragment pointers (per-lane): rows y0+wv*32+l16 (+16), k chunk q*8.
  // Wave covers 16 rows x 64 B = 16 full cache lines per load op.
  const u16* fU0 = Ub + (size_t)(y0 + wv * 32 + l16) * D_ + q * 8;
  const u16* fU1 = fU0 + (size_t)16 * D_;
  const u16* fW0 = Wb + (size_t)(y0 + wv * 32 + l16) * D_ + q * 8;
  const u16* fW1 = fW0 + (size_t)16 * D_;

  // X-fragment base (per-lane): row l0 + cl*16 + l16, k chunk q*8.
  // Same 16-line coalescing as A-frags; L2-resident via the swizzle.
  const u16* xbase = xb + ((size_t)b * LP + l16) * D_ + q * 8;

  // PER-LANE running softmax stats: lane covers cols (cl*16+l16), cl=0..7,
  // for each of its 8 y-rows (si = ry*4+r).
  float M[8], Z[8], W[8];
#pragma unroll
  for (int ii = 0; ii < 8; ++ii) { M[ii] = -1e30f; Z[ii] = 0.f; W[ii] = 0.f; }

  const f32x4 z4 = {0.f, 0.f, 0.f, 0.f};

  for (int ltl = 0; ltl < LTS; ++ltl) {
    const int l0 = (s * LTS + ltl) * BLK;
    const u16* xq0 = xbase + (size_t)l0 * D_;

    f32x4 accA[2][8], accS[2][8];
#pragma unroll
    for (int ry = 0; ry < 2; ++ry)
#pragma unroll
      for (int cl = 0; cl < 8; ++cl) { accA[ry][cl] = z4; accS[ry][cl] = z4; }

#pragma unroll 1
    for (int kt = 0; kt < NKT; ++kt) {
      const int ko = kt * BK;
      bf16x8 aU0 = *(const bf16x8*)(const void*)(fU0 + ko);
      bf16x8 aU1 = *(const bf16x8*)(const void*)(fU1 + ko);
      bf16x8 aW0 = *(const bf16x8*)(const void*)(fW0 + ko);
      bf16x8 aW1 = *(const bf16x8*)(const void*)(fW1 + ko);

      // half 1: cl 0..3
      bf16x8 xf[4];
#pragma unroll
      for (int cl = 0; cl < 4; ++cl)
        xf[cl] = *(const bf16x8*)(const void*)(xq0 + (size_t)cl * 16 * D_ + ko);
      __builtin_amdgcn_s_setprio(1);
#pragma unroll
      for (int cl = 0; cl < 4; ++cl) {
        accA[0][cl] = __builtin_amdgcn_mfma_f32_16x16x32_bf16(aU0, xf[cl], accA[0][cl], 0, 0, 0);
        accA[1][cl] = __builtin_amdgcn_mfma_f32_16x16x32_bf16(aU1, xf[cl], accA[1][cl], 0, 0, 0);
        accS[0][cl] = __builtin_amdgcn_mfma_f32_16x16x32_bf16(aW0, xf[cl], accS[0][cl], 0, 0, 0);
        accS[1][cl] = __builtin_amdgcn_mfma_f32_16x16x32_bf16(aW1, xf[cl], accS[1][cl], 0, 0, 0);
      }
      __builtin_amdgcn_s_setprio(0);

      // half 2: cl 4..7
#pragma unroll
      for (int cl = 0; cl < 4; ++cl)
        xf[cl] = *(const bf16x8*)(const void*)(xq0 + (size_t)(cl + 4) * 16 * D_ + ko);
      __builtin_amdgcn_s_setprio(1);
#pragma unroll
      for (int cl = 0; cl < 4; ++cl) {
        accA[0][cl + 4] = __builtin_amdgcn_mfma_f32_16x16x32_bf16(aU0, xf[cl], accA[0][cl + 4], 0, 0, 0);
        accA[1][cl + 4] = __builtin_amdgcn_mfma_f32_16x16x32_bf16(aU1, xf[cl], accA[1][cl + 4], 0, 0, 0);
        accS[0][cl + 4] = __builtin_amdgcn_mfma_f32_16x16x32_bf16(aW0, xf[cl], accS[0][cl + 4], 0, 0, 0);
        accS[1][cl + 4] = __builtin_amdgcn_mfma_f32_16x16x32_bf16(aW1, xf[cl], accS[1][cl + 4], 0, 0, 0);
      }
      __builtin_amdgcn_s_setprio(0);
    }

    // per-lane online softmax update. C/D: col(l)=lane&15, row(y)=q*4+reg
    const bool boundary = (l0 + BLK > L_);   // wave-uniform; 1 of 20 tiles
#pragma unroll
    for (int ry = 0; ry < 2; ++ry) {
#pragma unroll
      for (int r = 0; r < 4; ++r) {
        const int si = ry * 4 + r;
        float a[8];
        if (boundary) {
#pragma unroll
          for (int cl = 0; cl < 8; ++cl) {
            float v = accA[ry][cl][r];
            a[cl] = (l0 + cl * 16 + l16 >= L_) ? -1e30f : v;
          }
        } else {
#pragma unroll
          for (int cl = 0; cl < 8; ++cl) a[cl] = accA[ry][cl][r];
        }
        float tmax = a[0];
#pragma unroll
        for (int cl = 1; cl < 8; ++cl) tmax = fmaxf(tmax, a[cl]);
        const float mnew  = fmaxf(M[si], tmax);
        const float scale = __expf(M[si] - mnew);
        float zl = 0.f, wl = 0.f;
#pragma unroll
        for (int cl = 0; cl < 8; ++cl) {
          float p = __expf(a[cl] - mnew);
          zl += p;
          wl = fmaf(p, accS[ry][cl][r], wl);
        }
        Z[si] = fmaf(Z[si], scale, zl);
        W[si] = fmaf(W[si], scale, wl);
        M[si] = mnew;
      }
    }
  }

  // ONE cross-lane merge over the l16 group (butterfly with exp rescale)
#pragma unroll
  for (int si = 0; si < 8; ++si) {
    float M0 = M[si], Z0 = Z[si], W0 = W[si];
#pragma unroll
    for (int st = 1; st <= 8; st <<= 1) {
      const float Mo = __shfl_xor(M0, st);
      const float Zo = __shfl_xor(Z0, st);
      const float Wo = __shfl_xor(W0, st);
      const float mn = fmaxf(M0, Mo);
      const float sa = __expf(M0 - mn);
      const float sb = __expf(Mo - mn);
      Z0 = Z0 * sa + Zo * sb;
      W0 = W0 * sa + Wo * sb;
      M0 = mn;
    }
    M[si] = M0; Z[si] = Z0; W[si] = W0;
  }

  // write partial (M,Z,W) per owned y-row; stats now replicated -> l16==0 writes
  if (l16 == 0) {
    float* p = part + ((size_t)(b * 70 + yt) * NS + s) * 384;
#pragma unroll
    for (int ry = 0; ry < 2; ++ry) {
#pragma unroll
      for (int r = 0; r < 4; ++r) {
        const int si = ry * 4 + r;
        const int yl = wv * 32 + ry * 16 + q * 4 + r;
        p[yl]       = M[si];
        p[128 + yl] = Z[si];
        p[256 + yl] = W[si];
      }
    }
  }
}

// Merge NS partials per (b,y); y = W/Z + bias; BCE partial -> atomicAdd.
__global__ void combine_kernel(const float* __restrict__ part,
                               const float* __restrict__ bias,
                               const float* __restrict__ target,
                               float* __restrict__ out) {
  const int idx = blockIdx.x * 256 + threadIdx.x;
  float lpart = 0.f;
  if (idx < B_ * Y_) {
    const int b = idx / Y_;
    const int y = idx - b * Y_;
    const int yt = y >> 7, yl = y & 127;
    const float* p = part + ((size_t)(b * 70 + yt) * NS) * 384 + yl;
    float M = -1e30f;
#pragma unroll
    for (int s2 = 0; s2 < NS; ++s2) M = fmaxf(M, p[s2 * 384]);
    float Z = 0.f, W = 0.f;
#pragma unroll
    for (int s2 = 0; s2 < NS; ++s2) {
      const float e = __expf(p[s2 * 384] - M);
      Z = fmaf(p[s2 * 384 + 128], e, Z);
      W = fmaf(p[s2 * 384 + 256], e, W);
    }
    const float yv = W / Z + bias[y];
    out[idx] = yv;
    const float tg = target[idx];
    lpart = fmaxf(yv, 0.f) - yv * tg + log1pf(__expf(-fabsf(yv)));
  }
  lpart += __shfl_xor(lpart, 1);  lpart += __shfl_xor(lpart, 2);
  lpart += __shfl_xor(lpart, 4);  lpart += __shfl_xor(lpart, 8);
  lpart += __shfl_xor(lpart, 16); lpart += __shfl_xor(lpart, 32);
  if ((threadIdx.x & 63) == 0)
    atomicAdd(out + (size_t)B_ * Y_, lpart * (1.0f / (B_ * Y_)));
}

extern "C" void kernel_launch(void* const* d_in, const int* in_sizes, int n_in,
                              void* d_out, int out_size, void* d_ws, size_t ws_size,
                              hipStream_t stream) {
  const float* x      = (const float*)d_in[0];
  const float* target = (const float*)d_in[1];
  // d_in[2] = text_inputs (unused by reference)
  const float* U      = (const float*)d_in[3];
  const float* Wf     = (const float*)d_in[4];
  const float* bias   = (const float*)d_in[5];
  float* out = (float*)d_out;

  u16* xb = (u16*)d_ws;                      // [B][LP][D]   20.97 MB
  u16* Ub = xb + (size_t)B_ * LP * D_;       // [YP][D]       9.18 MB
  u16* Wb = Ub + (size_t)YP * D_;            // [YP][D]       9.18 MB
  float* part = (float*)(Wb + (size_t)YP * D_);  // [B][70][NS][384] f32  3.44 MB

  hipMemsetAsync(out + (size_t)B_ * Y_, 0, sizeof(float), stream);
  cvt_x_kernel<<<dim3((B_ * LP * 64) / 256), 256, 0, stream>>>(x, xb);
  cvt_w_kernel<<<dim3((2 * YP * 64) / 256), 256, 0, stream>>>(U, Wf, Ub, Wb);
  fused_kernel<<<dim3(NBLK), 256, 0, stream>>>(xb, Ub, Wb, part);
  combine_kernel<<<dim3((B_ * Y_ + 255) / 256), 256, 0, stream>>>(part, bias, target, out);
}